// Round 18
// baseline (304.588 us; speedup 1.0000x reference)
//
#include <hip/hip_runtime.h>
#include <hip/hip_bf16.h>
#include <math.h>

#define Bn   8
#define Ln   4096
#define DINn 128
#define Hn   256
#define N2n  8
#define NLn  4
#define NP   4   // mode pairs

typedef __attribute__((ext_vector_type(4))) float f32x4;
typedef __attribute__((ext_vector_type(2))) float f32x2;
typedef __attribute__((ext_vector_type(8))) short bf16x8;

__device__ __forceinline__ float gelu_f(float x) {
    float x2 = x * x;
    float inner = 0.7978845608028654f * x * fmaf(0.044715f, x2, 1.0f);
    float e = __expf(2.0f * inner);
    float th = 1.0f - 2.0f / (e + 1.0f);
    return 0.5f * x * (1.0f + th);
}

__device__ __forceinline__ float sigmoid_f(float x) {
    return 1.0f / (1.0f + __expf(-x));
}

__device__ __forceinline__ unsigned short f2bf(float f) {
    union { __hip_bfloat16 b; unsigned short u; } cv;
    cv.b = __float2bfloat16(f);
    return cv.u;
}

__device__ __forceinline__ uint4 pack8(float4 a, float4 b) {
    uint4 v;
    v.x = (unsigned)f2bf(a.x) | ((unsigned)f2bf(a.y) << 16);
    v.y = (unsigned)f2bf(a.z) | ((unsigned)f2bf(a.w) << 16);
    v.z = (unsigned)f2bf(b.x) | ((unsigned)f2bf(b.y) << 16);
    v.w = (unsigned)f2bf(b.z) | ((unsigned)f2bf(b.w) << 16);
    return v;
}

#define PKFMA(a, b, c) __builtin_elementwise_fma((f32x2)(a), (f32x2)(b), (f32x2)(c))

// ---------------------------------------------------------------------------
// S4D scan, 2 waves per row (r14-proven split math), block-linear LDS-staged
// I/O (exact HBM traffic), packed f32x2 arithmetic, two-pass form.
// Block = 256 thr = 4 waves = 2 rows; wave w -> row (w>>1), half (w&1);
// lane t owns 32-elem chunk.  grid (H/2, B) = 1024 blocks -> 4 blocks/CU,
// LDS 34KB -> 16 waves/CU (4/SIMD, 2x round-17).
// ---------------------------------------------------------------------------
__global__ __launch_bounds__(256, 4) void s4_scan_kernel(
    const float* __restrict__ hT,          // (B,H,L) f32
    unsigned short* __restrict__ yT,       // (B,H,L) bf16 out
    const float* __restrict__ log_dt,
    const float* __restrict__ log_A_real,
    const float* __restrict__ A_imag,
    const float* __restrict__ C_re,
    const float* __restrict__ C_im,
    const float* __restrict__ D_skip)
{
    __shared__ float uC[2 * 128 * 33];     // [row*128+chunk][33] (pad -> 2-way max)
    __shared__ float Sbuf[2][16];          // wave-A end states per row

    const int tid = threadIdx.x;
    const int w = tid >> 6;
    const int t = tid & 63;
    const int rowloc = w >> 1;
    const int half = w & 1;
    const int h = blockIdx.x * 2 + rowloc;
    const int b = blockIdx.y;

    // ---- load stage: 2 rows (32KB), block-linear, perfectly coalesced ----
    const float* gsrc = hT + (size_t)(b * Hn + blockIdx.x * 2) * Ln;
    #pragma unroll
    for (int it = 0; it < 8; ++it) {
        int idx4 = it * 256 + tid;
        float4 g = *(const float4*)(gsrc + (size_t)idx4 * 4);
        int e = idx4 * 4;
        int r = e >> 12, ep = e & 4095;
        int c = ep >> 5, off = ep & 31;
        *(float4*)(&uC[(r * 128 + c) * 33 + off]) = g;
    }
    __syncthreads();

    float* uL = &uC[(rowloc * 128 + half * 64 + t) * 33];

    // ---- per-mode params (wave-uniform), packed pairs ----
    float dt = expf(log_dt[h]);
    f32x2 wrp[NP], wip[NP], crp[NP], cip[NP];
    #pragma unroll
    for (int q = 0; q < NP; ++q) {
        #pragma unroll
        for (int e = 0; e < 2; ++e) {
            int n = 2 * q + e;
            float lar = log_A_real[h * N2n + n];
            float aim = A_imag[h * N2n + n];
            float are = -expf(lar);
            float mag = expf(are * dt);
            float s_, c_;
            sincosf(aim * dt, &s_, &c_);
            float w_re = mag * c_, w_im = mag * s_;
            float nre = w_re - 1.0f, nim = w_im;
            float inv = 1.0f / (are * are + aim * aim);
            float tre = (nre * are + nim * aim) * inv;
            float tim = (nim * are - nre * aim) * inv;
            float Cr = C_re[h * N2n + n], Ci = C_im[h * N2n + n];
            wrp[q][e] = w_re; wip[q][e] = w_im;
            crp[q][e] = Cr * tre - Ci * tim;
            cip[q][e] = Cr * tim + Ci * tre;
        }
    }
    const float Dsk = D_skip[h];

    // ---- phase 1: state-only local scan over 32 elems ----
    f32x2 srp[NP], sip[NP];
    #pragma unroll
    for (int q = 0; q < NP; ++q) { srp[q] = (f32x2)0.0f; sip[q] = (f32x2)0.0f; }
    #pragma unroll 4
    for (int j = 0; j < 32; ++j) {
        float u = uL[j];
        f32x2 uu = { u, u };
        #pragma unroll
        for (int q = 0; q < NP; ++q) {
            f32x2 nr = PKFMA(wrp[q], srp[q], PKFMA(-wip[q], sip[q], uu));
            f32x2 ni = PKFMA(wip[q], srp[q], wrp[q] * sip[q]);
            srp[q] = nr; sip[q] = ni;
        }
    }

    // ---- phase 2: KS (mult w^32, 5 squarings) + in-KS power w^(32t) ----
    f32x2 mrp[NP], mip[NP], arp[NP], aip[NP];
    #pragma unroll
    for (int q = 0; q < NP; ++q) {
        f32x2 ar = wrp[q], ai = wip[q];
        #pragma unroll
        for (int s = 0; s < 5; ++s) {
            f32x2 nr2 = ar * ar - ai * ai;
            ai = 2.0f * ar * ai;
            ar = nr2;
        }
        mrp[q] = ar; mip[q] = ai;          // w^32
        arp[q] = (f32x2)1.0f; aip[q] = (f32x2)0.0f;
    }
    #pragma unroll
    for (int dlt = 1; dlt < 64; dlt <<= 1) {
        #pragma unroll
        for (int q = 0; q < NP; ++q) {
            f32x2 tr, ti;
            tr.x = __shfl_up(srp[q].x, (unsigned)dlt, 64);
            tr.y = __shfl_up(srp[q].y, (unsigned)dlt, 64);
            ti.x = __shfl_up(sip[q].x, (unsigned)dlt, 64);
            ti.y = __shfl_up(sip[q].y, (unsigned)dlt, 64);
            f32x2 trz = (t >= dlt) ? tr : (f32x2)0.0f;
            f32x2 tiz = (t >= dlt) ? ti : (f32x2)0.0f;
            srp[q] = PKFMA(mrp[q], trz, PKFMA(-mip[q], tiz, srp[q]));
            sip[q] = PKFMA(mrp[q], tiz, PKFMA(mip[q], trz, sip[q]));
            // power build: acc *= mult (current = w^(32*dlt)) if bit set
            f32x2 nar = arp[q] * mrp[q] - aip[q] * mip[q];
            f32x2 nai = PKFMA(arp[q], mip[q], aip[q] * mrp[q]);
            bool bit = (t & dlt) != 0;
            arp[q] = bit ? nar : arp[q];
            aip[q] = bit ? nai : aip[q];
            // square multiplier
            f32x2 nr2 = mrp[q] * mrp[q] - mip[q] * mip[q];
            mip[q] = 2.0f * mrp[q] * mip[q];
            mrp[q] = nr2;
        }
    }

    // wave A publishes inclusive end state (lane 63)
    if (half == 0 && t == 63) {
        #pragma unroll
        for (int q = 0; q < NP; ++q) {
            Sbuf[rowloc][4 * q + 0] = srp[q].x;   // mode 2q   re
            Sbuf[rowloc][4 * q + 1] = sip[q].x;   // mode 2q   im
            Sbuf[rowloc][4 * q + 2] = srp[q].y;   // mode 2q+1 re
            Sbuf[rowloc][4 * q + 3] = sip[q].y;   // mode 2q+1 im
        }
    }
    // exclusive prefix within wave
    #pragma unroll
    for (int q = 0; q < NP; ++q) {
        f32x2 er, ei;
        er.x = __shfl_up(srp[q].x, 1u, 64);
        er.y = __shfl_up(srp[q].y, 1u, 64);
        ei.x = __shfl_up(sip[q].x, 1u, 64);
        ei.y = __shfl_up(sip[q].y, 1u, 64);
        srp[q] = (t >= 1) ? er : (f32x2)0.0f;
        sip[q] = (t >= 1) ? ei : (f32x2)0.0f;
    }
    __syncthreads();
    if (half == 1) {
        #pragma unroll
        for (int q = 0; q < NP; ++q) {
            f32x2 SAr = { Sbuf[rowloc][4 * q + 0], Sbuf[rowloc][4 * q + 2] };
            f32x2 SAi = { Sbuf[rowloc][4 * q + 1], Sbuf[rowloc][4 * q + 3] };
            srp[q] = PKFMA(arp[q], SAr, PKFMA(-aip[q], SAi, srp[q]));
            sip[q] = PKFMA(arp[q], SAi, PKFMA(aip[q], SAr, sip[q]));
        }
    }

    // ---- phase 3: recurrence from corrected state + projection + gelu;
    //      overwrite own LDS chunk with y (as f32) ----
    #pragma unroll 4
    for (int j = 0; j < 32; ++j) {
        float u = uL[j];
        f32x2 uu = { u, u };
        f32x2 accp = (f32x2)0.0f;
        #pragma unroll
        for (int q = 0; q < NP; ++q) {
            f32x2 nr = PKFMA(wrp[q], srp[q], PKFMA(-wip[q], sip[q], uu));
            f32x2 ni = PKFMA(wip[q], srp[q], wrp[q] * sip[q]);
            srp[q] = nr; sip[q] = ni;
            accp = PKFMA(crp[q], nr, PKFMA(-cip[q], ni, accp));
        }
        float acc = accp.x + accp.y;
        float yv = fmaf(2.0f, acc, Dsk * u);
        uL[j] = gelu_f(yv);
    }
    __syncthreads();

    // ---- store stage: block-linear bf16, perfectly coalesced ----
    unsigned short* gdst = yT + (size_t)(b * Hn + blockIdx.x * 2) * Ln;
    #pragma unroll
    for (int it = 0; it < 4; ++it) {
        int idx8 = it * 256 + tid;
        int e = idx8 * 8;
        int r = e >> 12, ep = e & 4095;
        int c = ep >> 5, off = ep & 31;
        const float* p = &uC[(r * 128 + c) * 33 + off];
        float4 ga = *(const float4*)p;
        float4 gb = *(const float4*)(p + 4);
        *(uint4*)(gdst + e) = pack8(ga, gb);
    }
}

// ---------------------------------------------------------------------------
// MFMA GEMM, residual-in-hT edition (byte-identical to round 13/15/17).
// ---------------------------------------------------------------------------
template<int KDIM, bool GLU, bool ACVT, bool KMAJ, bool LAST>
__global__ __launch_bounds__(256) void mfma_gemm(
    const unsigned short* __restrict__ Abf,   // KMAJ: yT (B,H,L)
    const float* __restrict__ Af,             // ACVT: x (M,KDIM) f32
    const float* __restrict__ W,
    const float* __restrict__ ba,
    const float* __restrict__ bg,
    float* hTbuf,                             // (B,256,L) f32 residual stream
    float* Hout)                              // LAST only: (M,256) f32
{
    constexpr int SM_MAIN = 128 * 72 * 2 + (GLU ? 2 : 1) * 64 * 72 * 2;
    constexpr int SM_TS = 64 * 132 * 4;
    constexpr int SM = SM_MAIN > SM_TS ? SM_MAIN : SM_TS;
    __shared__ __align__(16) char smem[SM];
    unsigned short* As  = (unsigned short*)smem;   // [128 rows][72]
    unsigned short* Bs0 = As + 128 * 72;           // [64][72]
    unsigned short* Bs1 = Bs0 + 64 * 72;           // GLU only
    float* ts = (float*)smem;                      // [64 n][132] reused

    const int tid = threadIdx.x;
    const int lane = tid & 63, w = tid >> 6;
    const int wm = w >> 1, wn = w & 1;
    const int lr = lane & 15, lq = lane >> 4;
    const int row0 = blockIdx.x * 128;
    const int n0 = blockIdx.y * 64;
    const int bb = row0 >> 12;
    const int l0 = row0 & (Ln - 1);

    f32x4 accA[4][2], accG[4][2];
    #pragma unroll
    for (int i = 0; i < 4; ++i)
        #pragma unroll
        for (int j = 0; j < 2; ++j) {
            accA[i][j] = (f32x4)0.0f;
            if constexpr (GLU) accG[i][j] = (f32x4)0.0f;
        }

    for (int kt = 0; kt < KDIM / 64; ++kt) {
        const int k0 = kt * 64;
        if constexpr (ACVT) {
            #pragma unroll
            for (int it = 0; it < 4; ++it) {
                int idx = it * 256 + tid; int m = idx >> 3, q = idx & 7;
                const float* s = Af + (size_t)(row0 + m) * KDIM + k0 + q * 8;
                float4 g1 = *(const float4*)s;
                float4 g2 = *(const float4*)(s + 4);
                *(uint4*)(&As[m * 72 + q * 8]) = pack8(g1, g2);
            }
        } else {
            #pragma unroll
            for (int it = 0; it < 4; ++it) {
                int p = tid >> 2;
                int c = (tid & 3) | (it << 2);
                uint4 g = *(const uint4*)(Abf + (size_t)(bb * Hn + k0 + p) * Ln + l0 + c * 8);
                unsigned short* d = &As[(c * 8) * 72 + p];
                d[0 * 72] = g.x & 0xffff; d[1 * 72] = g.x >> 16;
                d[2 * 72] = g.y & 0xffff; d[3 * 72] = g.y >> 16;
                d[4 * 72] = g.z & 0xffff; d[5 * 72] = g.z >> 16;
                d[6 * 72] = g.w & 0xffff; d[7 * 72] = g.w >> 16;
            }
        }
        #pragma unroll
        for (int it = 0; it < 2; ++it) {
            int idx = it * 256 + tid; int p = idx >> 3, q = idx & 7;
            {
                const float* s = W + (size_t)(n0 + p) * KDIM + k0 + q * 8;
                float4 g1 = *(const float4*)s;
                float4 g2 = *(const float4*)(s + 4);
                *(uint4*)(&Bs0[p * 72 + q * 8]) = pack8(g1, g2);
            }
            if constexpr (GLU) {
                const float* s = W + (size_t)(256 + n0 + p) * KDIM + k0 + q * 8;
                float4 g1 = *(const float4*)s;
                float4 g2 = *(const float4*)(s + 4);
                *(uint4*)(&Bs1[p * 72 + q * 8]) = pack8(g1, g2);
            }
        }
        __syncthreads();
        #pragma unroll
        for (int kf = 0; kf < 2; ++kf) {
            bf16x8 av[4], bv[2], gv[2];
            #pragma unroll
            for (int mf = 0; mf < 4; ++mf)
                av[mf] = *(const bf16x8*)(&As[(wm * 64 + mf * 16 + lr) * 72 + (kf * 4 + lq) * 8]);
            #pragma unroll
            for (int nf = 0; nf < 2; ++nf) {
                bv[nf] = *(const bf16x8*)(&Bs0[(wn * 32 + nf * 16 + lr) * 72 + (kf * 4 + lq) * 8]);
                if constexpr (GLU)
                    gv[nf] = *(const bf16x8*)(&Bs1[(wn * 32 + nf * 16 + lr) * 72 + (kf * 4 + lq) * 8]);
            }
            #pragma unroll
            for (int mf = 0; mf < 4; ++mf)
                #pragma unroll
                for (int nf = 0; nf < 2; ++nf) {
                    accA[mf][nf] = __builtin_amdgcn_mfma_f32_16x16x32_bf16(av[mf], bv[nf], accA[mf][nf], 0, 0, 0);
                    if constexpr (GLU)
                        accG[mf][nf] = __builtin_amdgcn_mfma_f32_16x16x32_bf16(av[mf], gv[nf], accG[mf][nf], 0, 0, 0);
                }
        }
        __syncthreads();
    }

    // ---- epilogue pass 1: raw (bias + GLU) -> ts[n_loc][m_loc], pitch 132 ----
    float bA[2], bG[2];
    #pragma unroll
    for (int nf = 0; nf < 2; ++nf) {
        int pc = n0 + wn * 32 + nf * 16 + lr;
        bA[nf] = ba[pc];
        if constexpr (GLU) bG[nf] = bg[pc];
    }
    #pragma unroll
    for (int mf = 0; mf < 4; ++mf) {
        #pragma unroll
        for (int r = 0; r < 4; ++r) {
            int m_loc = wm * 64 + mf * 16 + lq * 4 + r;
            #pragma unroll
            for (int nf = 0; nf < 2; ++nf) {
                float val;
                if constexpr (GLU) {
                    float aval = accA[mf][nf][r] + bA[nf];
                    float gval = accG[mf][nf][r] + bG[nf];
                    val = aval * sigmoid_f(gval);
                } else {
                    val = accA[mf][nf][r] + bA[nf];
                }
                ts[(wn * 32 + nf * 16 + lr) * 132 + m_loc] = val;
            }
        }
    }
    __syncthreads();

    if constexpr (!LAST) {
        #pragma unroll
        for (int it2 = 0; it2 < 8; ++it2) {
            int idx = it2 * 256 + tid;
            int nn = idx >> 5, m4 = (idx & 31) * 4;
            float4 o = *(const float4*)(&ts[nn * 132 + m4]);
            float* gp = hTbuf + (size_t)(bb * Hn + n0 + nn) * Ln + l0 + m4;
            if constexpr (GLU) {
                float4 rr = *(const float4*)gp;
                o.x += rr.x; o.y += rr.y; o.z += rr.z; o.w += rr.w;
            }
            *(float4*)gp = o;
        }
    } else {
        #pragma unroll
        for (int it2 = 0; it2 < 8; ++it2) {
            int idx = it2 * 256 + tid;
            int nn = idx >> 5, m4 = (idx & 31) * 4;
            float4 o = *(const float4*)(&ts[nn * 132 + m4]);
            const float* gp = hTbuf + (size_t)(bb * Hn + n0 + nn) * Ln + l0 + m4;
            float4 rr = *(const float4*)gp;
            o.x += rr.x; o.y += rr.y; o.z += rr.z; o.w += rr.w;
            *(float4*)(&ts[nn * 132 + m4]) = o;
        }
        __syncthreads();
        #pragma unroll
        for (int it2 = 0; it2 < 8; ++it2) {
            int idx = it2 * 256 + tid;
            int m = idx >> 4, n4 = (idx & 15) * 4;
            float4 o;
            o.x = ts[(n4 + 0) * 132 + m];
            o.y = ts[(n4 + 1) * 132 + m];
            o.z = ts[(n4 + 2) * 132 + m];
            o.w = ts[(n4 + 3) * 132 + m];
            *(float4*)(Hout + (size_t)(row0 + m) * Hn + n0 + n4) = o;
        }
    }
}

extern "C" void kernel_launch(void* const* d_in, const int* in_sizes, int n_in,
                              void* d_out, int out_size, void* d_ws, size_t ws_size,
                              hipStream_t stream) {
    (void)in_sizes; (void)n_in; (void)out_size; (void)ws_size;
    const float* x          = (const float*)d_in[0];
    const float* enc_w      = (const float*)d_in[1];
    const float* enc_b      = (const float*)d_in[2];
    const float* log_dt     = (const float*)d_in[3];
    const float* log_A_real = (const float*)d_in[4];
    const float* A_imag     = (const float*)d_in[5];
    const float* C_re       = (const float*)d_in[6];
    const float* C_im       = (const float*)d_in[7];
    const float* D_skip     = (const float*)d_in[8];
    const float* out_w      = (const float*)d_in[9];
    const float* out_b      = (const float*)d_in[10];

    const size_t NE = (size_t)Bn * Hn * Ln;
    float* h  = (float*)d_out;                        // (B,L,H) final output only
    float* hT = (float*)d_ws;                         // (B,256,L) f32 residual stream
    unsigned short* yT = (unsigned short*)(hT + NE);  // (B,H,L) bf16 scan output

    const dim3 gg(256, 4), gb(256);

    // encoder: hT = (x @ enc_w^T + enc_b)^T
    mfma_gemm<DINn, false, true, false, false><<<gg, gb, 0, stream>>>(
        nullptr, x, enc_w, enc_b, nullptr, hT, nullptr);

    for (int i = 0; i < NLn; ++i) {
        s4_scan_kernel<<<dim3(Hn / 2, Bn), gb, 0, stream>>>(
            hT, yT,
            log_dt + (size_t)i * Hn,
            log_A_real + (size_t)i * Hn * N2n,
            A_imag + (size_t)i * Hn * N2n,
            C_re + (size_t)i * Hn * N2n,
            C_im + (size_t)i * Hn * N2n,
            D_skip + (size_t)i * Hn);
        const float* wlay = out_w + (size_t)i * 2 * Hn * Hn;
        const float* bl = out_b + (size_t)i * 2 * Hn;
        if (i == NLn - 1) {
            mfma_gemm<Hn, true, false, true, true><<<gg, gb, 0, stream>>>(
                yT, nullptr, wlay, bl, bl + Hn, hT, h);
        } else {
            mfma_gemm<Hn, true, false, true, false><<<gg, gb, 0, stream>>>(
                yT, nullptr, wlay, bl, bl + Hn, hT, nullptr);
        }
    }
}

// Round 19
// 257.542 us; speedup vs baseline: 1.1827x; 1.1827x over previous
//
#include <hip/hip_runtime.h>
#include <hip/hip_bf16.h>
#include <math.h>

#define Bn   8
#define Ln   4096
#define DINn 128
#define Hn   256
#define N2n  8
#define NLn  4
#define NP   4   // mode pairs

typedef __attribute__((ext_vector_type(4))) float f32x4;
typedef __attribute__((ext_vector_type(2))) float f32x2;
typedef __attribute__((ext_vector_type(8))) short bf16x8;

__device__ __forceinline__ float gelu_f(float x) {
    float x2 = x * x;
    float inner = 0.7978845608028654f * x * fmaf(0.044715f, x2, 1.0f);
    float e = __expf(2.0f * inner);
    float th = 1.0f - 2.0f / (e + 1.0f);
    return 0.5f * x * (1.0f + th);
}

__device__ __forceinline__ float sigmoid_f(float x) {
    return 1.0f / (1.0f + __expf(-x));
}

__device__ __forceinline__ unsigned short f2bf(float f) {
    union { __hip_bfloat16 b; unsigned short u; } cv;
    cv.b = __float2bfloat16(f);
    return cv.u;
}

__device__ __forceinline__ uint4 pack8(float4 a, float4 b) {
    uint4 v;
    v.x = (unsigned)f2bf(a.x) | ((unsigned)f2bf(a.y) << 16);
    v.y = (unsigned)f2bf(a.z) | ((unsigned)f2bf(a.w) << 16);
    v.z = (unsigned)f2bf(b.x) | ((unsigned)f2bf(b.y) << 16);
    v.w = (unsigned)f2bf(b.z) | ((unsigned)f2bf(b.w) << 16);
    return v;
}

#define PKFMA(a, b, c) __builtin_elementwise_fma((f32x2)(a), (f32x2)(b), (f32x2)(c))

// ---------------------------------------------------------------------------
// S4D scan — round-17 version verbatim (best passing): wave-per-row, packed
// f32x2 arithmetic, two-pass form (phase 1 state-only, phase 3 recurrence
// from KS-corrected state with projection+D-skip+gelu fused).
// grid (H/4, B), block 256 = 4 independent waves.
// ---------------------------------------------------------------------------
__global__ __launch_bounds__(256) void s4_scan_kernel(
    const float* __restrict__ hT,          // (B,H,L) f32
    unsigned short* __restrict__ yT,       // (B,H,L) bf16 out
    const float* __restrict__ log_dt,
    const float* __restrict__ log_A_real,
    const float* __restrict__ A_imag,
    const float* __restrict__ C_re,
    const float* __restrict__ C_im,
    const float* __restrict__ D_skip)
{
    __shared__ float u_lds[4][64][65];
    const int tid = threadIdx.x;
    const int v = tid >> 6;
    const int t = tid & 63;
    const int h = blockIdx.x * 4 + v;
    const int b = blockIdx.y;

    const size_t rowbase = (size_t)(b * Hn + h) * Ln + (size_t)t * 64;
    const float* src = hT + rowbase;
    float* uL = &u_lds[v][t][0];

    #pragma unroll
    for (int j4 = 0; j4 < 16; ++j4) {
        float4 g = *(const float4*)(src + j4 * 4);
        uL[j4 * 4 + 0] = g.x; uL[j4 * 4 + 1] = g.y;
        uL[j4 * 4 + 2] = g.z; uL[j4 * 4 + 3] = g.w;
    }

    float dt = expf(log_dt[h]);
    f32x2 wrp[NP], wip[NP], crp[NP], cip[NP];
    #pragma unroll
    for (int q = 0; q < NP; ++q) {
        #pragma unroll
        for (int e = 0; e < 2; ++e) {
            int n = 2 * q + e;
            float lar = log_A_real[h * N2n + n];
            float aim = A_imag[h * N2n + n];
            float are = -expf(lar);
            float mag = expf(are * dt);
            float s_, c_;
            sincosf(aim * dt, &s_, &c_);
            float w_re = mag * c_, w_im = mag * s_;
            float nre = w_re - 1.0f, nim = w_im;
            float inv = 1.0f / (are * are + aim * aim);
            float tre = (nre * are + nim * aim) * inv;
            float tim = (nim * are - nre * aim) * inv;
            float Cr = C_re[h * N2n + n], Ci = C_im[h * N2n + n];
            wrp[q][e] = w_re; wip[q][e] = w_im;
            crp[q][e] = Cr * tre - Ci * tim;
            cip[q][e] = Cr * tim + Ci * tre;
        }
    }
    const float Dsk = D_skip[h];

    // ---- phase 1: state-only local scan (no projection, no LDS write) ----
    f32x2 srp[NP], sip[NP];
    #pragma unroll
    for (int q = 0; q < NP; ++q) { srp[q] = (f32x2)0.0f; sip[q] = (f32x2)0.0f; }
    #pragma unroll 4
    for (int j = 0; j < 64; ++j) {
        float u = uL[j];
        f32x2 uu = { u, u };
        #pragma unroll
        for (int q = 0; q < NP; ++q) {
            f32x2 nr = PKFMA(wrp[q], srp[q], PKFMA(-wip[q], sip[q], uu));
            f32x2 ni = PKFMA(wip[q], srp[q], wrp[q] * sip[q]);
            srp[q] = nr; sip[q] = ni;
        }
    }

    // ---- phase 2: inclusive wave scan of end-states, multiplier w^64 ----
    f32x2 mrp[NP], mip[NP];
    #pragma unroll
    for (int q = 0; q < NP; ++q) {
        f32x2 ar = wrp[q], ai = wip[q];
        #pragma unroll
        for (int s = 0; s < 6; ++s) {
            f32x2 nr2 = ar * ar - ai * ai;
            ai = 2.0f * ar * ai;
            ar = nr2;
        }
        mrp[q] = ar; mip[q] = ai;   // w^64
    }
    for (int dlt = 1; dlt < 64; dlt <<= 1) {
        #pragma unroll
        for (int q = 0; q < NP; ++q) {
            f32x2 tr, ti;
            tr.x = __shfl_up(srp[q].x, (unsigned)dlt, 64);
            tr.y = __shfl_up(srp[q].y, (unsigned)dlt, 64);
            ti.x = __shfl_up(sip[q].x, (unsigned)dlt, 64);
            ti.y = __shfl_up(sip[q].y, (unsigned)dlt, 64);
            f32x2 trz = (t >= dlt) ? tr : (f32x2)0.0f;
            f32x2 tiz = (t >= dlt) ? ti : (f32x2)0.0f;
            srp[q] = PKFMA(mrp[q], trz, PKFMA(-mip[q], tiz, srp[q]));
            sip[q] = PKFMA(mrp[q], tiz, PKFMA(mip[q], trz, sip[q]));
        }
        #pragma unroll
        for (int q = 0; q < NP; ++q) {
            f32x2 nr2 = mrp[q] * mrp[q] - mip[q] * mip[q];
            mip[q] = 2.0f * mrp[q] * mip[q];
            mrp[q] = nr2;
        }
    }
    // exclusive prefix = incoming state for this lane's chunk
    #pragma unroll
    for (int q = 0; q < NP; ++q) {
        f32x2 er, ei;
        er.x = __shfl_up(srp[q].x, 1u, 64);
        er.y = __shfl_up(srp[q].y, 1u, 64);
        ei.x = __shfl_up(sip[q].x, 1u, 64);
        ei.y = __shfl_up(sip[q].y, 1u, 64);
        srp[q] = (t >= 1) ? er : (f32x2)0.0f;
        sip[q] = (t >= 1) ? ei : (f32x2)0.0f;
    }

    // ---- phase 3: recurrence from corrected state + projection + gelu ----
    unsigned short* dst = yT + rowbase;
    for (int j8 = 0; j8 < 8; ++j8) {
        unsigned short rs[8];
        #pragma unroll
        for (int c = 0; c < 8; ++c) {
            float u = uL[j8 * 8 + c];
            f32x2 uu = { u, u };
            f32x2 accp = (f32x2)0.0f;
            #pragma unroll
            for (int q = 0; q < NP; ++q) {
                f32x2 nr = PKFMA(wrp[q], srp[q], PKFMA(-wip[q], sip[q], uu));
                f32x2 ni = PKFMA(wip[q], srp[q], wrp[q] * sip[q]);
                srp[q] = nr; sip[q] = ni;
                accp = PKFMA(crp[q], nr, PKFMA(-cip[q], ni, accp));
            }
            float acc = accp.x + accp.y;
            float yv = fmaf(2.0f, acc, Dsk * u);
            rs[c] = f2bf(gelu_f(yv));
        }
        uint4 o;
        o.x = (unsigned)rs[0] | ((unsigned)rs[1] << 16);
        o.y = (unsigned)rs[2] | ((unsigned)rs[3] << 16);
        o.z = (unsigned)rs[4] | ((unsigned)rs[5] << 16);
        o.w = (unsigned)rs[6] | ((unsigned)rs[7] << 16);
        *(uint4*)(dst + j8 * 8) = o;
    }
}

// ---------------------------------------------------------------------------
// MFMA GEMM, residual-in-hT edition (byte-identical to round 13/15/17).
// ---------------------------------------------------------------------------
template<int KDIM, bool GLU, bool ACVT, bool KMAJ, bool LAST>
__global__ __launch_bounds__(256) void mfma_gemm(
    const unsigned short* __restrict__ Abf,   // KMAJ: yT (B,H,L)
    const float* __restrict__ Af,             // ACVT: x (M,KDIM) f32
    const float* __restrict__ W,
    const float* __restrict__ ba,
    const float* __restrict__ bg,
    float* hTbuf,                             // (B,256,L) f32 residual stream
    float* Hout)                              // LAST only: (M,256) f32
{
    constexpr int SM_MAIN = 128 * 72 * 2 + (GLU ? 2 : 1) * 64 * 72 * 2;
    constexpr int SM_TS = 64 * 132 * 4;
    constexpr int SM = SM_MAIN > SM_TS ? SM_MAIN : SM_TS;
    __shared__ __align__(16) char smem[SM];
    unsigned short* As  = (unsigned short*)smem;   // [128 rows][72]
    unsigned short* Bs0 = As + 128 * 72;           // [64][72]
    unsigned short* Bs1 = Bs0 + 64 * 72;           // GLU only
    float* ts = (float*)smem;                      // [64 n][132] reused

    const int tid = threadIdx.x;
    const int lane = tid & 63, w = tid >> 6;
    const int wm = w >> 1, wn = w & 1;
    const int lr = lane & 15, lq = lane >> 4;
    const int row0 = blockIdx.x * 128;
    const int n0 = blockIdx.y * 64;
    const int bb = row0 >> 12;
    const int l0 = row0 & (Ln - 1);

    f32x4 accA[4][2], accG[4][2];
    #pragma unroll
    for (int i = 0; i < 4; ++i)
        #pragma unroll
        for (int j = 0; j < 2; ++j) {
            accA[i][j] = (f32x4)0.0f;
            if constexpr (GLU) accG[i][j] = (f32x4)0.0f;
        }

    for (int kt = 0; kt < KDIM / 64; ++kt) {
        const int k0 = kt * 64;
        if constexpr (ACVT) {
            #pragma unroll
            for (int it = 0; it < 4; ++it) {
                int idx = it * 256 + tid; int m = idx >> 3, q = idx & 7;
                const float* s = Af + (size_t)(row0 + m) * KDIM + k0 + q * 8;
                float4 g1 = *(const float4*)s;
                float4 g2 = *(const float4*)(s + 4);
                *(uint4*)(&As[m * 72 + q * 8]) = pack8(g1, g2);
            }
        } else {
            #pragma unroll
            for (int it = 0; it < 4; ++it) {
                int p = tid >> 2;
                int c = (tid & 3) | (it << 2);
                uint4 g = *(const uint4*)(Abf + (size_t)(bb * Hn + k0 + p) * Ln + l0 + c * 8);
                unsigned short* d = &As[(c * 8) * 72 + p];
                d[0 * 72] = g.x & 0xffff; d[1 * 72] = g.x >> 16;
                d[2 * 72] = g.y & 0xffff; d[3 * 72] = g.y >> 16;
                d[4 * 72] = g.z & 0xffff; d[5 * 72] = g.z >> 16;
                d[6 * 72] = g.w & 0xffff; d[7 * 72] = g.w >> 16;
            }
        }
        #pragma unroll
        for (int it = 0; it < 2; ++it) {
            int idx = it * 256 + tid; int p = idx >> 3, q = idx & 7;
            {
                const float* s = W + (size_t)(n0 + p) * KDIM + k0 + q * 8;
                float4 g1 = *(const float4*)s;
                float4 g2 = *(const float4*)(s + 4);
                *(uint4*)(&Bs0[p * 72 + q * 8]) = pack8(g1, g2);
            }
            if constexpr (GLU) {
                const float* s = W + (size_t)(256 + n0 + p) * KDIM + k0 + q * 8;
                float4 g1 = *(const float4*)s;
                float4 g2 = *(const float4*)(s + 4);
                *(uint4*)(&Bs1[p * 72 + q * 8]) = pack8(g1, g2);
            }
        }
        __syncthreads();
        #pragma unroll
        for (int kf = 0; kf < 2; ++kf) {
            bf16x8 av[4], bv[2], gv[2];
            #pragma unroll
            for (int mf = 0; mf < 4; ++mf)
                av[mf] = *(const bf16x8*)(&As[(wm * 64 + mf * 16 + lr) * 72 + (kf * 4 + lq) * 8]);
            #pragma unroll
            for (int nf = 0; nf < 2; ++nf) {
                bv[nf] = *(const bf16x8*)(&Bs0[(wn * 32 + nf * 16 + lr) * 72 + (kf * 4 + lq) * 8]);
                if constexpr (GLU)
                    gv[nf] = *(const bf16x8*)(&Bs1[(wn * 32 + nf * 16 + lr) * 72 + (kf * 4 + lq) * 8]);
            }
            #pragma unroll
            for (int mf = 0; mf < 4; ++mf)
                #pragma unroll
                for (int nf = 0; nf < 2; ++nf) {
                    accA[mf][nf] = __builtin_amdgcn_mfma_f32_16x16x32_bf16(av[mf], bv[nf], accA[mf][nf], 0, 0, 0);
                    if constexpr (GLU)
                        accG[mf][nf] = __builtin_amdgcn_mfma_f32_16x16x32_bf16(av[mf], gv[nf], accG[mf][nf], 0, 0, 0);
                }
        }
        __syncthreads();
    }

    // ---- epilogue pass 1: raw (bias + GLU) -> ts[n_loc][m_loc], pitch 132 ----
    float bA[2], bG[2];
    #pragma unroll
    for (int nf = 0; nf < 2; ++nf) {
        int pc = n0 + wn * 32 + nf * 16 + lr;
        bA[nf] = ba[pc];
        if constexpr (GLU) bG[nf] = bg[pc];
    }
    #pragma unroll
    for (int mf = 0; mf < 4; ++mf) {
        #pragma unroll
        for (int r = 0; r < 4; ++r) {
            int m_loc = wm * 64 + mf * 16 + lq * 4 + r;
            #pragma unroll
            for (int nf = 0; nf < 2; ++nf) {
                float val;
                if constexpr (GLU) {
                    float aval = accA[mf][nf][r] + bA[nf];
                    float gval = accG[mf][nf][r] + bG[nf];
                    val = aval * sigmoid_f(gval);
                } else {
                    val = accA[mf][nf][r] + bA[nf];
                }
                ts[(wn * 32 + nf * 16 + lr) * 132 + m_loc] = val;
            }
        }
    }
    __syncthreads();

    if constexpr (!LAST) {
        #pragma unroll
        for (int it2 = 0; it2 < 8; ++it2) {
            int idx = it2 * 256 + tid;
            int nn = idx >> 5, m4 = (idx & 31) * 4;
            float4 o = *(const float4*)(&ts[nn * 132 + m4]);
            float* gp = hTbuf + (size_t)(bb * Hn + n0 + nn) * Ln + l0 + m4;
            if constexpr (GLU) {
                float4 rr = *(const float4*)gp;
                o.x += rr.x; o.y += rr.y; o.z += rr.z; o.w += rr.w;
            }
            *(float4*)gp = o;
        }
    } else {
        #pragma unroll
        for (int it2 = 0; it2 < 8; ++it2) {
            int idx = it2 * 256 + tid;
            int nn = idx >> 5, m4 = (idx & 31) * 4;
            float4 o = *(const float4*)(&ts[nn * 132 + m4]);
            const float* gp = hTbuf + (size_t)(bb * Hn + n0 + nn) * Ln + l0 + m4;
            float4 rr = *(const float4*)gp;
            o.x += rr.x; o.y += rr.y; o.z += rr.z; o.w += rr.w;
            *(float4*)(&ts[nn * 132 + m4]) = o;
        }
        __syncthreads();
        #pragma unroll
        for (int it2 = 0; it2 < 8; ++it2) {
            int idx = it2 * 256 + tid;
            int m = idx >> 4, n4 = (idx & 15) * 4;
            float4 o;
            o.x = ts[(n4 + 0) * 132 + m];
            o.y = ts[(n4 + 1) * 132 + m];
            o.z = ts[(n4 + 2) * 132 + m];
            o.w = ts[(n4 + 3) * 132 + m];
            *(float4*)(Hout + (size_t)(row0 + m) * Hn + n0 + n4) = o;
        }
    }
}

extern "C" void kernel_launch(void* const* d_in, const int* in_sizes, int n_in,
                              void* d_out, int out_size, void* d_ws, size_t ws_size,
                              hipStream_t stream) {
    (void)in_sizes; (void)n_in; (void)out_size; (void)ws_size;
    const float* x          = (const float*)d_in[0];
    const float* enc_w      = (const float*)d_in[1];
    const float* enc_b      = (const float*)d_in[2];
    const float* log_dt     = (const float*)d_in[3];
    const float* log_A_real = (const float*)d_in[4];
    const float* A_imag     = (const float*)d_in[5];
    const float* C_re       = (const float*)d_in[6];
    const float* C_im       = (const float*)d_in[7];
    const float* D_skip     = (const float*)d_in[8];
    const float* out_w      = (const float*)d_in[9];
    const float* out_b      = (const float*)d_in[10];

    const size_t NE = (size_t)Bn * Hn * Ln;
    float* h  = (float*)d_out;                        // (B,L,H) final output only
    float* hT = (float*)d_ws;                         // (B,256,L) f32 residual stream
    unsigned short* yT = (unsigned short*)(hT + NE);  // (B,H,L) bf16 scan output

    const dim3 gg(256, 4), gb(256);

    // encoder: hT = (x @ enc_w^T + enc_b)^T
    mfma_gemm<DINn, false, true, false, false><<<gg, gb, 0, stream>>>(
        nullptr, x, enc_w, enc_b, nullptr, hT, nullptr);

    for (int i = 0; i < NLn; ++i) {
        s4_scan_kernel<<<dim3(Hn / 4, Bn), gb, 0, stream>>>(
            hT, yT,
            log_dt + (size_t)i * Hn,
            log_A_real + (size_t)i * Hn * N2n,
            A_imag + (size_t)i * Hn * N2n,
            C_re + (size_t)i * Hn * N2n,
            C_im + (size_t)i * Hn * N2n,
            D_skip + (size_t)i * Hn);
        const float* wlay = out_w + (size_t)i * 2 * Hn * Hn;
        const float* bl = out_b + (size_t)i * 2 * Hn;
        if (i == NLn - 1) {
            mfma_gemm<Hn, true, false, true, true><<<gg, gb, 0, stream>>>(
                yT, nullptr, wlay, bl, bl + Hn, hT, h);
        } else {
            mfma_gemm<Hn, true, false, true, false><<<gg, gb, 0, stream>>>(
                yT, nullptr, wlay, bl, bl + Hn, hT, nullptr);
        }
    }
}

// Round 20
// 256.699 us; speedup vs baseline: 1.1866x; 1.0033x over previous
//
#include <hip/hip_runtime.h>
#include <hip/hip_bf16.h>
#include <math.h>

#define Bn   8
#define Ln   4096
#define DINn 128
#define Hn   256
#define N2n  8
#define NLn  4
#define NP   4   // mode pairs

typedef __attribute__((ext_vector_type(4))) float f32x4;
typedef __attribute__((ext_vector_type(2))) float f32x2;
typedef __attribute__((ext_vector_type(8))) short bf16x8;

__device__ __forceinline__ float gelu_f(float x) {
    float x2 = x * x;
    float inner = 0.7978845608028654f * x * fmaf(0.044715f, x2, 1.0f);
    float e = __expf(2.0f * inner);
    float th = 1.0f - 2.0f / (e + 1.0f);
    return 0.5f * x * (1.0f + th);
}

__device__ __forceinline__ float sigmoid_f(float x) {
    return 1.0f / (1.0f + __expf(-x));
}

__device__ __forceinline__ unsigned short f2bf(float f) {
    union { __hip_bfloat16 b; unsigned short u; } cv;
    cv.b = __float2bfloat16(f);
    return cv.u;
}

__device__ __forceinline__ uint4 pack8(float4 a, float4 b) {
    uint4 v;
    v.x = (unsigned)f2bf(a.x) | ((unsigned)f2bf(a.y) << 16);
    v.y = (unsigned)f2bf(a.z) | ((unsigned)f2bf(a.w) << 16);
    v.z = (unsigned)f2bf(b.x) | ((unsigned)f2bf(b.y) << 16);
    v.w = (unsigned)f2bf(b.z) | ((unsigned)f2bf(b.w) << 16);
    return v;
}

#define PKFMA(a, b, c) __builtin_elementwise_fma((f32x2)(a), (f32x2)(b), (f32x2)(c))

// ---------------------------------------------------------------------------
// S4D scan — r17 structure (wave-per-row, packed f32x2, two-pass), with
// step-doubled recurrences to halve the serial dependence chain:
//   phase 1: step-4  s4 = w^4*s + [w^2*(w u1+u2) + (w u3+u4)]  (T off-chain)
//   phase 3: step-2  s2 = w^2*s + (w u1+u2) on-chain; s1 = w*s+u1 side-branch
// grid (H/4, B), block 256 = 4 independent waves.
// ---------------------------------------------------------------------------
__global__ __launch_bounds__(256) void s4_scan_kernel(
    const float* __restrict__ hT,          // (B,H,L) f32
    unsigned short* __restrict__ yT,       // (B,H,L) bf16 out
    const float* __restrict__ log_dt,
    const float* __restrict__ log_A_real,
    const float* __restrict__ A_imag,
    const float* __restrict__ C_re,
    const float* __restrict__ C_im,
    const float* __restrict__ D_skip)
{
    __shared__ float u_lds[4][64][65];
    const int tid = threadIdx.x;
    const int v = tid >> 6;
    const int t = tid & 63;
    const int h = blockIdx.x * 4 + v;
    const int b = blockIdx.y;

    const size_t rowbase = (size_t)(b * Hn + h) * Ln + (size_t)t * 64;
    const float* src = hT + rowbase;
    float* uL = &u_lds[v][t][0];

    #pragma unroll
    for (int j4 = 0; j4 < 16; ++j4) {
        float4 g = *(const float4*)(src + j4 * 4);
        uL[j4 * 4 + 0] = g.x; uL[j4 * 4 + 1] = g.y;
        uL[j4 * 4 + 2] = g.z; uL[j4 * 4 + 3] = g.w;
    }

    float dt = expf(log_dt[h]);
    f32x2 wrp[NP], wip[NP], crp[NP], cip[NP];
    #pragma unroll
    for (int q = 0; q < NP; ++q) {
        #pragma unroll
        for (int e = 0; e < 2; ++e) {
            int n = 2 * q + e;
            float lar = log_A_real[h * N2n + n];
            float aim = A_imag[h * N2n + n];
            float are = -expf(lar);
            float mag = expf(are * dt);
            float s_, c_;
            sincosf(aim * dt, &s_, &c_);
            float w_re = mag * c_, w_im = mag * s_;
            float nre = w_re - 1.0f, nim = w_im;
            float inv = 1.0f / (are * are + aim * aim);
            float tre = (nre * are + nim * aim) * inv;
            float tim = (nim * are - nre * aim) * inv;
            float Cr = C_re[h * N2n + n], Ci = C_im[h * N2n + n];
            wrp[q][e] = w_re; wip[q][e] = w_im;
            crp[q][e] = Cr * tre - Ci * tim;
            cip[q][e] = Cr * tim + Ci * tre;
        }
    }
    const float Dsk = D_skip[h];

    // w^2 and w^4 (per mode pair)
    f32x2 w2r[NP], w2i[NP], w4r[NP], w4i[NP];
    #pragma unroll
    for (int q = 0; q < NP; ++q) {
        w2r[q] = wrp[q] * wrp[q] - wip[q] * wip[q];
        w2i[q] = 2.0f * wrp[q] * wip[q];
        w4r[q] = w2r[q] * w2r[q] - w2i[q] * w2i[q];
        w4i[q] = 2.0f * w2r[q] * w2i[q];
    }

    // ---- phase 1: state-only local scan, step-4 ----
    f32x2 srp[NP], sip[NP];
    #pragma unroll
    for (int q = 0; q < NP; ++q) { srp[q] = (f32x2)0.0f; sip[q] = (f32x2)0.0f; }
    #pragma unroll 4
    for (int g = 0; g < 16; ++g) {
        float u1 = uL[4 * g + 0], u2 = uL[4 * g + 1];
        float u3 = uL[4 * g + 2], u4 = uL[4 * g + 3];
        f32x2 uu1 = { u1, u1 }, uu2 = { u2, u2 };
        f32x2 uu3 = { u3, u3 }, uu4 = { u4, u4 };
        #pragma unroll
        for (int q = 0; q < NP; ++q) {
            f32x2 tar = PKFMA(wrp[q], uu1, uu2);
            f32x2 tai = wip[q] * uu1;
            f32x2 tbr = PKFMA(wrp[q], uu3, uu4);
            f32x2 tbi = wip[q] * uu3;
            f32x2 Tr = PKFMA(w2r[q], tar, PKFMA(-w2i[q], tai, tbr));
            f32x2 Ti = PKFMA(w2i[q], tar, PKFMA(w2r[q], tai, tbi));
            f32x2 nr = PKFMA(w4r[q], srp[q], PKFMA(-w4i[q], sip[q], Tr));
            f32x2 ni = PKFMA(w4i[q], srp[q], PKFMA(w4r[q], sip[q], Ti));
            srp[q] = nr; sip[q] = ni;
        }
    }

    // ---- phase 2: inclusive wave scan of end-states, multiplier w^64 ----
    f32x2 mrp[NP], mip[NP];
    #pragma unroll
    for (int q = 0; q < NP; ++q) {
        f32x2 ar = w4r[q], ai = w4i[q];
        #pragma unroll
        for (int s = 0; s < 4; ++s) {
            f32x2 nr2 = ar * ar - ai * ai;
            ai = 2.0f * ar * ai;
            ar = nr2;
        }
        mrp[q] = ar; mip[q] = ai;   // w^64
    }
    for (int dlt = 1; dlt < 64; dlt <<= 1) {
        #pragma unroll
        for (int q = 0; q < NP; ++q) {
            f32x2 tr, ti;
            tr.x = __shfl_up(srp[q].x, (unsigned)dlt, 64);
            tr.y = __shfl_up(srp[q].y, (unsigned)dlt, 64);
            ti.x = __shfl_up(sip[q].x, (unsigned)dlt, 64);
            ti.y = __shfl_up(sip[q].y, (unsigned)dlt, 64);
            f32x2 trz = (t >= dlt) ? tr : (f32x2)0.0f;
            f32x2 tiz = (t >= dlt) ? ti : (f32x2)0.0f;
            srp[q] = PKFMA(mrp[q], trz, PKFMA(-mip[q], tiz, srp[q]));
            sip[q] = PKFMA(mrp[q], tiz, PKFMA(mip[q], trz, sip[q]));
        }
        #pragma unroll
        for (int q = 0; q < NP; ++q) {
            f32x2 nr2 = mrp[q] * mrp[q] - mip[q] * mip[q];
            mip[q] = 2.0f * mrp[q] * mip[q];
            mrp[q] = nr2;
        }
    }
    // exclusive prefix = incoming state for this lane's chunk
    #pragma unroll
    for (int q = 0; q < NP; ++q) {
        f32x2 er, ei;
        er.x = __shfl_up(srp[q].x, 1u, 64);
        er.y = __shfl_up(srp[q].y, 1u, 64);
        ei.x = __shfl_up(sip[q].x, 1u, 64);
        ei.y = __shfl_up(sip[q].y, 1u, 64);
        srp[q] = (t >= 1) ? er : (f32x2)0.0f;
        sip[q] = (t >= 1) ? ei : (f32x2)0.0f;
    }

    // ---- phase 3: step-2 recurrence + projection + gelu ----
    unsigned short* dst = yT + rowbase;
    for (int j8 = 0; j8 < 8; ++j8) {
        unsigned short rs[8];
        #pragma unroll
        for (int c2 = 0; c2 < 4; ++c2) {
            float u1 = uL[j8 * 8 + 2 * c2];
            float u2 = uL[j8 * 8 + 2 * c2 + 1];
            f32x2 uu1 = { u1, u1 }, uu2 = { u2, u2 };
            f32x2 acc1 = (f32x2)0.0f, acc2 = (f32x2)0.0f;
            #pragma unroll
            for (int q = 0; q < NP; ++q) {
                // t = w*u1 + u2 (off-chain)
                f32x2 tar = PKFMA(wrp[q], uu1, uu2);
                f32x2 tai = wip[q] * uu1;
                // side branch: s1 = w*s0 + u1
                f32x2 nr1 = PKFMA(wrp[q], srp[q], PKFMA(-wip[q], sip[q], uu1));
                f32x2 ni1 = PKFMA(wip[q], srp[q], wrp[q] * sip[q]);
                // main chain: s2 = w^2*s0 + t
                f32x2 nr2 = PKFMA(w2r[q], srp[q], PKFMA(-w2i[q], sip[q], tar));
                f32x2 ni2 = PKFMA(w2i[q], srp[q], PKFMA(w2r[q], sip[q], tai));
                srp[q] = nr2; sip[q] = ni2;
                acc1 = PKFMA(crp[q], nr1, PKFMA(-cip[q], ni1, acc1));
                acc2 = PKFMA(crp[q], nr2, PKFMA(-cip[q], ni2, acc2));
            }
            float a1 = acc1.x + acc1.y;
            float a2 = acc2.x + acc2.y;
            float y1 = fmaf(2.0f, a1, Dsk * u1);
            float y2 = fmaf(2.0f, a2, Dsk * u2);
            rs[2 * c2]     = f2bf(gelu_f(y1));
            rs[2 * c2 + 1] = f2bf(gelu_f(y2));
        }
        uint4 o;
        o.x = (unsigned)rs[0] | ((unsigned)rs[1] << 16);
        o.y = (unsigned)rs[2] | ((unsigned)rs[3] << 16);
        o.z = (unsigned)rs[4] | ((unsigned)rs[5] << 16);
        o.w = (unsigned)rs[6] | ((unsigned)rs[7] << 16);
        *(uint4*)(dst + j8 * 8) = o;
    }
}

// ---------------------------------------------------------------------------
// MFMA GEMM, residual-in-hT edition (byte-identical to round 13/15/17/19).
// ---------------------------------------------------------------------------
template<int KDIM, bool GLU, bool ACVT, bool KMAJ, bool LAST>
__global__ __launch_bounds__(256) void mfma_gemm(
    const unsigned short* __restrict__ Abf,   // KMAJ: yT (B,H,L)
    const float* __restrict__ Af,             // ACVT: x (M,KDIM) f32
    const float* __restrict__ W,
    const float* __restrict__ ba,
    const float* __restrict__ bg,
    float* hTbuf,                             // (B,256,L) f32 residual stream
    float* Hout)                              // LAST only: (M,256) f32
{
    constexpr int SM_MAIN = 128 * 72 * 2 + (GLU ? 2 : 1) * 64 * 72 * 2;
    constexpr int SM_TS = 64 * 132 * 4;
    constexpr int SM = SM_MAIN > SM_TS ? SM_MAIN : SM_TS;
    __shared__ __align__(16) char smem[SM];
    unsigned short* As  = (unsigned short*)smem;   // [128 rows][72]
    unsigned short* Bs0 = As + 128 * 72;           // [64][72]
    unsigned short* Bs1 = Bs0 + 64 * 72;           // GLU only
    float* ts = (float*)smem;                      // [64 n][132] reused

    const int tid = threadIdx.x;
    const int lane = tid & 63, w = tid >> 6;
    const int wm = w >> 1, wn = w & 1;
    const int lr = lane & 15, lq = lane >> 4;
    const int row0 = blockIdx.x * 128;
    const int n0 = blockIdx.y * 64;
    const int bb = row0 >> 12;
    const int l0 = row0 & (Ln - 1);

    f32x4 accA[4][2], accG[4][2];
    #pragma unroll
    for (int i = 0; i < 4; ++i)
        #pragma unroll
        for (int j = 0; j < 2; ++j) {
            accA[i][j] = (f32x4)0.0f;
            if constexpr (GLU) accG[i][j] = (f32x4)0.0f;
        }

    for (int kt = 0; kt < KDIM / 64; ++kt) {
        const int k0 = kt * 64;
        if constexpr (ACVT) {
            #pragma unroll
            for (int it = 0; it < 4; ++it) {
                int idx = it * 256 + tid; int m = idx >> 3, q = idx & 7;
                const float* s = Af + (size_t)(row0 + m) * KDIM + k0 + q * 8;
                float4 g1 = *(const float4*)s;
                float4 g2 = *(const float4*)(s + 4);
                *(uint4*)(&As[m * 72 + q * 8]) = pack8(g1, g2);
            }
        } else {
            #pragma unroll
            for (int it = 0; it < 4; ++it) {
                int p = tid >> 2;
                int c = (tid & 3) | (it << 2);
                uint4 g = *(const uint4*)(Abf + (size_t)(bb * Hn + k0 + p) * Ln + l0 + c * 8);
                unsigned short* d = &As[(c * 8) * 72 + p];
                d[0 * 72] = g.x & 0xffff; d[1 * 72] = g.x >> 16;
                d[2 * 72] = g.y & 0xffff; d[3 * 72] = g.y >> 16;
                d[4 * 72] = g.z & 0xffff; d[5 * 72] = g.z >> 16;
                d[6 * 72] = g.w & 0xffff; d[7 * 72] = g.w >> 16;
            }
        }
        #pragma unroll
        for (int it = 0; it < 2; ++it) {
            int idx = it * 256 + tid; int p = idx >> 3, q = idx & 7;
            {
                const float* s = W + (size_t)(n0 + p) * KDIM + k0 + q * 8;
                float4 g1 = *(const float4*)s;
                float4 g2 = *(const float4*)(s + 4);
                *(uint4*)(&Bs0[p * 72 + q * 8]) = pack8(g1, g2);
            }
            if constexpr (GLU) {
                const float* s = W + (size_t)(256 + n0 + p) * KDIM + k0 + q * 8;
                float4 g1 = *(const float4*)s;
                float4 g2 = *(const float4*)(s + 4);
                *(uint4*)(&Bs1[p * 72 + q * 8]) = pack8(g1, g2);
            }
        }
        __syncthreads();
        #pragma unroll
        for (int kf = 0; kf < 2; ++kf) {
            bf16x8 av[4], bv[2], gv[2];
            #pragma unroll
            for (int mf = 0; mf < 4; ++mf)
                av[mf] = *(const bf16x8*)(&As[(wm * 64 + mf * 16 + lr) * 72 + (kf * 4 + lq) * 8]);
            #pragma unroll
            for (int nf = 0; nf < 2; ++nf) {
                bv[nf] = *(const bf16x8*)(&Bs0[(wn * 32 + nf * 16 + lr) * 72 + (kf * 4 + lq) * 8]);
                if constexpr (GLU)
                    gv[nf] = *(const bf16x8*)(&Bs1[(wn * 32 + nf * 16 + lr) * 72 + (kf * 4 + lq) * 8]);
            }
            #pragma unroll
            for (int mf = 0; mf < 4; ++mf)
                #pragma unroll
                for (int nf = 0; nf < 2; ++nf) {
                    accA[mf][nf] = __builtin_amdgcn_mfma_f32_16x16x32_bf16(av[mf], bv[nf], accA[mf][nf], 0, 0, 0);
                    if constexpr (GLU)
                        accG[mf][nf] = __builtin_amdgcn_mfma_f32_16x16x32_bf16(av[mf], gv[nf], accG[mf][nf], 0, 0, 0);
                }
        }
        __syncthreads();
    }

    // ---- epilogue pass 1: raw (bias + GLU) -> ts[n_loc][m_loc], pitch 132 ----
    float bA[2], bG[2];
    #pragma unroll
    for (int nf = 0; nf < 2; ++nf) {
        int pc = n0 + wn * 32 + nf * 16 + lr;
        bA[nf] = ba[pc];
        if constexpr (GLU) bG[nf] = bg[pc];
    }
    #pragma unroll
    for (int mf = 0; mf < 4; ++mf) {
        #pragma unroll
        for (int r = 0; r < 4; ++r) {
            int m_loc = wm * 64 + mf * 16 + lq * 4 + r;
            #pragma unroll
            for (int nf = 0; nf < 2; ++nf) {
                float val;
                if constexpr (GLU) {
                    float aval = accA[mf][nf][r] + bA[nf];
                    float gval = accG[mf][nf][r] + bG[nf];
                    val = aval * sigmoid_f(gval);
                } else {
                    val = accA[mf][nf][r] + bA[nf];
                }
                ts[(wn * 32 + nf * 16 + lr) * 132 + m_loc] = val;
            }
        }
    }
    __syncthreads();

    if constexpr (!LAST) {
        #pragma unroll
        for (int it2 = 0; it2 < 8; ++it2) {
            int idx = it2 * 256 + tid;
            int nn = idx >> 5, m4 = (idx & 31) * 4;
            float4 o = *(const float4*)(&ts[nn * 132 + m4]);
            float* gp = hTbuf + (size_t)(bb * Hn + n0 + nn) * Ln + l0 + m4;
            if constexpr (GLU) {
                float4 rr = *(const float4*)gp;
                o.x += rr.x; o.y += rr.y; o.z += rr.z; o.w += rr.w;
            }
            *(float4*)gp = o;
        }
    } else {
        #pragma unroll
        for (int it2 = 0; it2 < 8; ++it2) {
            int idx = it2 * 256 + tid;
            int nn = idx >> 5, m4 = (idx & 31) * 4;
            float4 o = *(const float4*)(&ts[nn * 132 + m4]);
            const float* gp = hTbuf + (size_t)(bb * Hn + n0 + nn) * Ln + l0 + m4;
            float4 rr = *(const float4*)gp;
            o.x += rr.x; o.y += rr.y; o.z += rr.z; o.w += rr.w;
            *(float4*)(&ts[nn * 132 + m4]) = o;
        }
        __syncthreads();
        #pragma unroll
        for (int it2 = 0; it2 < 8; ++it2) {
            int idx = it2 * 256 + tid;
            int m = idx >> 4, n4 = (idx & 15) * 4;
            float4 o;
            o.x = ts[(n4 + 0) * 132 + m];
            o.y = ts[(n4 + 1) * 132 + m];
            o.z = ts[(n4 + 2) * 132 + m];
            o.w = ts[(n4 + 3) * 132 + m];
            *(float4*)(Hout + (size_t)(row0 + m) * Hn + n0 + n4) = o;
        }
    }
}

extern "C" void kernel_launch(void* const* d_in, const int* in_sizes, int n_in,
                              void* d_out, int out_size, void* d_ws, size_t ws_size,
                              hipStream_t stream) {
    (void)in_sizes; (void)n_in; (void)out_size; (void)ws_size;
    const float* x          = (const float*)d_in[0];
    const float* enc_w      = (const float*)d_in[1];
    const float* enc_b      = (const float*)d_in[2];
    const float* log_dt     = (const float*)d_in[3];
    const float* log_A_real = (const float*)d_in[4];
    const float* A_imag     = (const float*)d_in[5];
    const float* C_re       = (const float*)d_in[6];
    const float* C_im       = (const float*)d_in[7];
    const float* D_skip     = (const float*)d_in[8];
    const float* out_w      = (const float*)d_in[9];
    const float* out_b      = (const float*)d_in[10];

    const size_t NE = (size_t)Bn * Hn * Ln;
    float* h  = (float*)d_out;                        // (B,L,H) final output only
    float* hT = (float*)d_ws;                         // (B,256,L) f32 residual stream
    unsigned short* yT = (unsigned short*)(hT + NE);  // (B,H,L) bf16 scan output

    const dim3 gg(256, 4), gb(256);

    // encoder: hT = (x @ enc_w^T + enc_b)^T
    mfma_gemm<DINn, false, true, false, false><<<gg, gb, 0, stream>>>(
        nullptr, x, enc_w, enc_b, nullptr, hT, nullptr);

    for (int i = 0; i < NLn; ++i) {
        s4_scan_kernel<<<dim3(Hn / 4, Bn), gb, 0, stream>>>(
            hT, yT,
            log_dt + (size_t)i * Hn,
            log_A_real + (size_t)i * Hn * N2n,
            A_imag + (size_t)i * Hn * N2n,
            C_re + (size_t)i * Hn * N2n,
            C_im + (size_t)i * Hn * N2n,
            D_skip + (size_t)i * Hn);
        const float* wlay = out_w + (size_t)i * 2 * Hn * Hn;
        const float* bl = out_b + (size_t)i * 2 * Hn;
        if (i == NLn - 1) {
            mfma_gemm<Hn, true, false, true, true><<<gg, gb, 0, stream>>>(
                yT, nullptr, wlay, bl, bl + Hn, hT, h);
        } else {
            mfma_gemm<Hn, true, false, true, false><<<gg, gb, 0, stream>>>(
                yT, nullptr, wlay, bl, bl + Hn, hT, nullptr);
        }
    }
}